// Round 1
// baseline (555.639 us; speedup 1.0000x reference)
//
#include <hip/hip_runtime.h>

#define DIN 150528
#define DD 512
#define NC 100
#define NM 64
#define NFEAT 256
#define EPSF 1e-6f
#define KSTEPS (DIN / 32) /* 4704 */

typedef float f32x4 __attribute__((ext_vector_type(4)));
typedef __bf16 bf16x8 __attribute__((ext_vector_type(8)));
typedef unsigned short u16x8 __attribute__((ext_vector_type(8)));

static __device__ __forceinline__ unsigned short f2bf(float x) {
  unsigned int u = __builtin_bit_cast(unsigned int, x);
  u += 0x7FFFu + ((u >> 16) & 1u);  // RNE
  return (unsigned short)(u >> 16);
}
static __device__ __forceinline__ float bf2f(unsigned short h) {
  return __builtin_bit_cast(float, ((unsigned int)h) << 16);
}

// ---------------------------------------------------------------------------
// Kernel 1: f = image @ W_enc, split-K over 256 blocks, atomicAdd fp32.
// Block: 256 threads = 4 waves; wave w owns N-range [w*128, w*128+128).
// No LDS: W fragments direct-from-global (4x64B segments/inst), A via float4.
// MFMA 16x16x32 bf16: A[m=lane&15][k=quad*8+j], B[k=quad*8+j][n=lane&15],
// C: col=lane&15, row=quad*4+reg (learn_hip m89-verified layouts).
// ---------------------------------------------------------------------------
__global__ __launch_bounds__(256, 1) void gemm_f(
    const float* __restrict__ image, const float* __restrict__ W,
    float* __restrict__ f_buf) {
  const int tid = threadIdx.x;
  const int wv = tid >> 6;
  const int lane = tid & 63;
  const int q = lane >> 4;
  const int r16 = lane & 15;
  const int nb = wv * 128;

  f32x4 acc[4][8];
#pragma unroll
  for (int mt = 0; mt < 4; ++mt)
#pragma unroll
    for (int nt = 0; nt < 8; ++nt)
#pragma unroll
      for (int r = 0; r < 4; ++r) acc[mt][nt][r] = 0.0f;

  const int b = blockIdx.x;                 // grid must be 256
  const int s0 = (b * KSTEPS) >> 8;
  const int s1 = ((b + 1) * KSTEPS) >> 8;

  for (int s = s0; s < s1; ++s) {
    const int k0 = s * 32;
    f32x4 alo[4], ahi[4];
#pragma unroll
    for (int mt = 0; mt < 4; ++mt) {
      const float* ap = image + (size_t)(mt * 16 + r16) * DIN + (k0 + q * 8);
      alo[mt] = *(const f32x4*)ap;
      ahi[mt] = *(const f32x4*)(ap + 4);
    }
    float wr[8][8];
#pragma unroll
    for (int nt = 0; nt < 8; ++nt) {
      const float* wp = W + (size_t)(k0 + q * 8) * DD + (nb + nt * 16 + r16);
#pragma unroll
      for (int j = 0; j < 8; ++j) wr[nt][j] = wp[(size_t)j * DD];
    }
    bf16x8 av[4];
#pragma unroll
    for (int mt = 0; mt < 4; ++mt) {
      u16x8 u;
      u[0] = f2bf(alo[mt][0]); u[1] = f2bf(alo[mt][1]);
      u[2] = f2bf(alo[mt][2]); u[3] = f2bf(alo[mt][3]);
      u[4] = f2bf(ahi[mt][0]); u[5] = f2bf(ahi[mt][1]);
      u[6] = f2bf(ahi[mt][2]); u[7] = f2bf(ahi[mt][3]);
      av[mt] = __builtin_bit_cast(bf16x8, u);
    }
    bf16x8 bv[8];
#pragma unroll
    for (int nt = 0; nt < 8; ++nt) {
      u16x8 u;
#pragma unroll
      for (int j = 0; j < 8; ++j) u[j] = f2bf(wr[nt][j]);
      bv[nt] = __builtin_bit_cast(bf16x8, u);
    }
#pragma unroll
    for (int mt = 0; mt < 4; ++mt)
#pragma unroll
      for (int nt = 0; nt < 8; ++nt)
        acc[mt][nt] = __builtin_amdgcn_mfma_f32_16x16x32_bf16(
            av[mt], bv[nt], acc[mt][nt], 0, 0, 0);
  }

#pragma unroll
  for (int mt = 0; mt < 4; ++mt)
#pragma unroll
    for (int nt = 0; nt < 8; ++nt) {
      const int n = nb + nt * 16 + r16;
#pragma unroll
      for (int r = 0; r < 4; ++r) {
        const int m = mt * 16 + q * 4 + r;
        atomicAdd(f_buf + m * DD + n, acc[mt][nt][r]);
      }
    }
}

// ---------------------------------------------------------------------------
// Kernel 2: row-normalize f -> fn. grid 64 x 64 threads.
// ---------------------------------------------------------------------------
__global__ void norm_f(const float* __restrict__ f, float* __restrict__ fn) {
  const int b = blockIdx.x;
  const int t = threadIdx.x;  // 64
  float s = 0.0f;
#pragma unroll
  for (int i = 0; i < 8; ++i) {
    float v = f[b * DD + t + i * 64];
    s += v * v;
  }
#pragma unroll
  for (int o = 32; o; o >>= 1) s += __shfl_xor(s, o);
  const float inv = 1.0f / sqrtf(s);
#pragma unroll
  for (int i = 0; i < 8; ++i)
    fn[b * DD + t + i * 64] = f[b * DD + t + i * 64] * inv;
}

// ---------------------------------------------------------------------------
// Kernel 3: per class c: gather keys_sel (64x256) & text_sel (100x256),
// L = keys_sel @ text_sel^T via bf16 MFMA (M=64,N=112pad,K=256, K in 2 halves
// to fit 64KB LDS), softmax over j2, p_cc -> w[m], then kw[c][j]=sum_m w*ksel.
// ---------------------------------------------------------------------------
__global__ __launch_bounds__(256) void wk_kernel(
    const float* __restrict__ text, const float* __restrict__ keys,
    const int* __restrict__ indices, const float* __restrict__ pgamma,
    float* __restrict__ kw_buf) {
  const int c = blockIdx.x;
  const int t = threadIdx.x;
  const int wv = t >> 6, lane = t & 63;
  const int q = lane >> 4, r16 = lane & 15;

  __shared__ __align__(16) unsigned short A_lds[64 * 264];   // 33792 B, full K
  __shared__ __align__(16) unsigned short B_lds[112 * 136];  // 30464 B, K-half
  __shared__ __align__(16) int idx_s[256];                   // 1024 B

  idx_s[t] = indices[c * 256 + t];
  __syncthreads();

  // Gather A (keys_sel) full K, bf16. thread t = column j.
  {
    const int j = t;
    const float* kp = keys + (size_t)c * 64 * 512 + idx_s[j];
#pragma unroll 8
    for (int m = 0; m < 64; ++m) A_lds[m * 264 + j] = f2bf(kp[(size_t)m * 512]);
  }

  f32x4 acc[7];
#pragma unroll
  for (int nt = 0; nt < 7; ++nt)
#pragma unroll
    for (int r = 0; r < 4; ++r) acc[nt][r] = 0.0f;
  const int mt = wv;

  for (int kh = 0; kh < 2; ++kh) {
    __syncthreads();  // previous B reads (or A writes) complete
    {
      const int kk = t & 127;
      const float* tp = text + idx_s[kh * 128 + kk];
      for (int n = (t >> 7); n < 112; n += 2)
        B_lds[n * 136 + kk] =
            (n < NC) ? f2bf(tp[(size_t)n * 512]) : (unsigned short)0;
    }
    __syncthreads();
#pragma unroll
    for (int ks = 0; ks < 4; ++ks) {
      bf16x8 afr = *(const bf16x8*)(A_lds + (mt * 16 + r16) * 264 + kh * 128 +
                                    ks * 32 + q * 8);
#pragma unroll
      for (int nt = 0; nt < 7; ++nt) {
        bf16x8 bfr =
            *(const bf16x8*)(B_lds + (nt * 16 + r16) * 136 + ks * 32 + q * 8);
        acc[nt] = __builtin_amdgcn_mfma_f32_16x16x32_bf16(afr, bfr, acc[nt],
                                                          0, 0, 0);
      }
    }
  }
  __syncthreads();

  // C (64x113 fp32) overlays B_lds (28928 <= 30464 B).
  float* C_lds = reinterpret_cast<float*>(B_lds);
#pragma unroll
  for (int nt = 0; nt < 7; ++nt) {
    const int j2 = nt * 16 + r16;
#pragma unroll
    for (int r = 0; r < 4; ++r) {
      const int m = mt * 16 + q * 4 + r;
      C_lds[m * 113 + j2] = acc[nt][r];
    }
  }
  __syncthreads();

  float* w_lds = reinterpret_cast<float*>(idx_s);  // idx no longer needed
  if (t < 64) {
    const int m = t;
    float mx = -1e30f;
    for (int j2 = 0; j2 < NC; ++j2) mx = fmaxf(mx, C_lds[m * 113 + j2]);
    float sum = 0.0f;
    for (int j2 = 0; j2 < NC; ++j2) sum += expf(C_lds[m * 113 + j2] - mx);
    const float p = expf(C_lds[m * 113 + c] - mx) / sum;
    const float KL = log2f((1.0f + EPSF) / (p + EPSF));
    w_lds[m] = expf(KL * (*pgamma));
  }
  __syncthreads();
  {
    const int j = t;
    float kwv = 0.0f;
#pragma unroll 8
    for (int m = 0; m < 64; ++m) kwv += w_lds[m] * bf2f(A_lds[m * 264 + j]);
    kw_buf[c * 256 + j] = kwv;
  }
}

// ---------------------------------------------------------------------------
// Kernel 4: out[b][c] = alpha*exp(beta*cache-beta) + exp(ls)*dot(fn_b,text_c)
// cache = (1/64) * sum_j fn[b][idx[c][j]] * kw[c][j].  grid 100 x 256.
// ---------------------------------------------------------------------------
__global__ __launch_bounds__(256) void final_kernel(
    const float* __restrict__ fn, const float* __restrict__ text,
    const int* __restrict__ indices, const float* __restrict__ kw_buf,
    const float* __restrict__ pls, const float* __restrict__ palpha,
    const float* __restrict__ pbeta, float* __restrict__ out) {
  const int c = blockIdx.x;
  const int t = threadIdx.x;
  const int wv = t >> 6, lane = t & 63;
  __shared__ float redc[4], redl[4];

  const int myidx = indices[c * 256 + t];
  const float mykw = kw_buf[c * 256 + t];
  const float tc0 = text[c * 512 + t];
  const float tc1 = text[c * 512 + 256 + t];
  const float ls = expf(*pls);
  const float alpha = *palpha, beta = *pbeta;

  for (int b = 0; b < 64; ++b) {
    const float* fr = fn + b * 512;
    float cp = fr[myidx] * mykw;
    float lp = fr[t] * tc0 + fr[t + 256] * tc1;
#pragma unroll
    for (int o = 32; o; o >>= 1) {
      cp += __shfl_xor(cp, o);
      lp += __shfl_xor(lp, o);
    }
    if (lane == 0) { redc[wv] = cp; redl[wv] = lp; }
    __syncthreads();
    if (t == 0) {
      const float cache = (redc[0] + redc[1] + redc[2] + redc[3]) * (1.0f / 64.0f);
      const float clip = (redl[0] + redl[1] + redl[2] + redl[3]) * ls;
      out[b * 100 + c] = alpha * expf(beta * cache - beta) + clip;
    }
    __syncthreads();
  }
}

// ---------------------------------------------------------------------------
extern "C" void kernel_launch(void* const* d_in, const int* in_sizes, int n_in,
                              void* d_out, int out_size, void* d_ws,
                              size_t ws_size, hipStream_t stream) {
  const float* image = (const float*)d_in[0];
  const float* W = (const float*)d_in[1];
  const float* text = (const float*)d_in[2];
  const float* keys = (const float*)d_in[3];
  const float* pls = (const float*)d_in[4];
  const int* idx = (const int*)d_in[5];
  const float* palpha = (const float*)d_in[6];
  const float* pbeta = (const float*)d_in[7];
  const float* pgamma = (const float*)d_in[8];
  float* out = (float*)d_out;

  char* ws = (char*)d_ws;
  float* f_buf = (float*)(ws);             // 64*512*4   = 131072 B
  float* fn = (float*)(ws + 131072);       // 64*512*4   = 131072 B
  float* kw = (float*)(ws + 262144);       // 100*256*4  = 102400 B

  hipMemsetAsync(f_buf, 0, 64 * 512 * sizeof(float), stream);
  gemm_f<<<256, 256, 0, stream>>>(image, W, f_buf);
  norm_f<<<64, 64, 0, stream>>>(f_buf, fn);
  wk_kernel<<<NC, 256, 0, stream>>>(text, keys, idx, pgamma, kw);
  final_kernel<<<NC, 256, 0, stream>>>(fn, text, idx, kw, pls, palpha, pbeta,
                                       out);
}

// Round 2
// 510.254 us; speedup vs baseline: 1.0889x; 1.0889x over previous
//
#include <hip/hip_runtime.h>

#define DIN 150528
#define DD 512
#define NC 100
#define NM 64
#define NFEAT 256
#define EPSF 1e-6f
#define KSTEPS (DIN / 32) /* 4704 */

typedef float f32x4 __attribute__((ext_vector_type(4)));
typedef __bf16 bf16x8 __attribute__((ext_vector_type(8)));
typedef unsigned short u16x8 __attribute__((ext_vector_type(8)));

static __device__ __forceinline__ unsigned short f2bf(float x) {
  unsigned int u = __builtin_bit_cast(unsigned int, x);
  u += 0x7FFFu + ((u >> 16) & 1u);  // RNE
  return (unsigned short)(u >> 16);
}
static __device__ __forceinline__ float bf2f(unsigned short h) {
  return __builtin_bit_cast(float, ((unsigned int)h) << 16);
}

// ---------------------------------------------------------------------------
// Kernel 1: f_part[s] = image @ W_enc (k-slice s), split-K over 256 blocks.
// Plain coalesced stores of per-block partials — NO atomics (the round-1
// version funneled 8.4M device-scope atomicAdds into 128 KB; serialized tail).
// Block: 256 threads = 4 waves; wave w owns N-range [w*128, w*128+128).
// No LDS: W fragments direct-from-global (4x64B segments/inst), A via float4.
// MFMA 16x16x32 bf16: A[m=lane&15][k=quad*8+j], B[k=quad*8+j][n=lane&15],
// C: col=lane&15, row=quad*4+reg (learn_hip m89-verified layouts).
// ---------------------------------------------------------------------------
__global__ __launch_bounds__(256, 1) void gemm_f(
    const float* __restrict__ image, const float* __restrict__ W,
    float* __restrict__ f_part) {
  const int tid = threadIdx.x;
  const int wv = tid >> 6;
  const int lane = tid & 63;
  const int q = lane >> 4;
  const int r16 = lane & 15;
  const int nb = wv * 128;

  f32x4 acc[4][8];
#pragma unroll
  for (int mt = 0; mt < 4; ++mt)
#pragma unroll
    for (int nt = 0; nt < 8; ++nt)
#pragma unroll
      for (int r = 0; r < 4; ++r) acc[mt][nt][r] = 0.0f;

  const int b = blockIdx.x;                 // grid must be 256
  const int s0 = (b * KSTEPS) >> 8;
  const int s1 = ((b + 1) * KSTEPS) >> 8;

  for (int s = s0; s < s1; ++s) {
    const int k0 = s * 32;
    f32x4 alo[4], ahi[4];
#pragma unroll
    for (int mt = 0; mt < 4; ++mt) {
      const float* ap = image + (size_t)(mt * 16 + r16) * DIN + (k0 + q * 8);
      alo[mt] = *(const f32x4*)ap;
      ahi[mt] = *(const f32x4*)(ap + 4);
    }
    float wr[8][8];
#pragma unroll
    for (int nt = 0; nt < 8; ++nt) {
      const float* wp = W + (size_t)(k0 + q * 8) * DD + (nb + nt * 16 + r16);
#pragma unroll
      for (int j = 0; j < 8; ++j) wr[nt][j] = wp[(size_t)j * DD];
    }
    bf16x8 av[4];
#pragma unroll
    for (int mt = 0; mt < 4; ++mt) {
      u16x8 u;
      u[0] = f2bf(alo[mt][0]); u[1] = f2bf(alo[mt][1]);
      u[2] = f2bf(alo[mt][2]); u[3] = f2bf(alo[mt][3]);
      u[4] = f2bf(ahi[mt][0]); u[5] = f2bf(ahi[mt][1]);
      u[6] = f2bf(ahi[mt][2]); u[7] = f2bf(ahi[mt][3]);
      av[mt] = __builtin_bit_cast(bf16x8, u);
    }
    bf16x8 bv[8];
#pragma unroll
    for (int nt = 0; nt < 8; ++nt) {
      u16x8 u;
#pragma unroll
      for (int j = 0; j < 8; ++j) u[j] = f2bf(wr[nt][j]);
      bv[nt] = __builtin_bit_cast(bf16x8, u);
    }
#pragma unroll
    for (int mt = 0; mt < 4; ++mt)
#pragma unroll
      for (int nt = 0; nt < 8; ++nt)
        acc[mt][nt] = __builtin_amdgcn_mfma_f32_16x16x32_bf16(
            av[mt], bv[nt], acc[mt][nt], 0, 0, 0);
  }

  float* outp = f_part + (size_t)b * (NM * DD);
#pragma unroll
  for (int mt = 0; mt < 4; ++mt)
#pragma unroll
    for (int nt = 0; nt < 8; ++nt) {
      const int n = nb + nt * 16 + r16;
#pragma unroll
      for (int r = 0; r < 4; ++r) {
        const int m = mt * 16 + q * 4 + r;
        outp[m * DD + n] = acc[mt][nt][r];
      }
    }
}

// ---------------------------------------------------------------------------
// Kernel 1b: f[m][n] = sum_s f_part[s][m][n]. Grid 256 = (64 m) x (4 n-chunks),
// 128 threads = one column each, fully coalesced (512B per s per wave-half).
// ---------------------------------------------------------------------------
__global__ __launch_bounds__(128) void reduce_f(
    const float* __restrict__ f_part, float* __restrict__ f) {
  const int m = blockIdx.x >> 2;
  const int n = (blockIdx.x & 3) * 128 + threadIdx.x;
  const float* p = f_part + (size_t)m * DD + n;
  float s = 0.0f;
#pragma unroll 16
  for (int sdx = 0; sdx < 256; ++sdx) s += p[(size_t)sdx * (NM * DD)];
  f[m * DD + n] = s;
}

// ---------------------------------------------------------------------------
// Kernel 2: row-normalize f -> fn. grid 64 x 64 threads.
// ---------------------------------------------------------------------------
__global__ void norm_f(const float* __restrict__ f, float* __restrict__ fn) {
  const int b = blockIdx.x;
  const int t = threadIdx.x;  // 64
  float s = 0.0f;
#pragma unroll
  for (int i = 0; i < 8; ++i) {
    float v = f[b * DD + t + i * 64];
    s += v * v;
  }
#pragma unroll
  for (int o = 32; o; o >>= 1) s += __shfl_xor(s, o);
  const float inv = 1.0f / sqrtf(s);
#pragma unroll
  for (int i = 0; i < 8; ++i)
    fn[b * DD + t + i * 64] = f[b * DD + t + i * 64] * inv;
}

// ---------------------------------------------------------------------------
// Kernel 3: per class c: gather keys_sel (64x256) & text_sel (100x256),
// L = keys_sel @ text_sel^T via bf16 MFMA (M=64,N=112pad,K=256, K in 2 halves
// to fit 64KB LDS), softmax over j2, p_cc -> w[m], then kw[c][j]=sum_m w*ksel.
// ---------------------------------------------------------------------------
__global__ __launch_bounds__(256) void wk_kernel(
    const float* __restrict__ text, const float* __restrict__ keys,
    const int* __restrict__ indices, const float* __restrict__ pgamma,
    float* __restrict__ kw_buf) {
  const int c = blockIdx.x;
  const int t = threadIdx.x;
  const int wv = t >> 6, lane = t & 63;
  const int q = lane >> 4, r16 = lane & 15;

  __shared__ __align__(16) unsigned short A_lds[64 * 264];   // 33792 B, full K
  __shared__ __align__(16) unsigned short B_lds[112 * 136];  // 30464 B, K-half
  __shared__ __align__(16) int idx_s[256];                   // 1024 B

  idx_s[t] = indices[c * 256 + t];
  __syncthreads();

  // Gather A (keys_sel) full K, bf16. thread t = column j.
  {
    const int j = t;
    const float* kp = keys + (size_t)c * 64 * 512 + idx_s[j];
#pragma unroll 8
    for (int m = 0; m < 64; ++m) A_lds[m * 264 + j] = f2bf(kp[(size_t)m * 512]);
  }

  f32x4 acc[7];
#pragma unroll
  for (int nt = 0; nt < 7; ++nt)
#pragma unroll
    for (int r = 0; r < 4; ++r) acc[nt][r] = 0.0f;
  const int mt = wv;

  for (int kh = 0; kh < 2; ++kh) {
    __syncthreads();  // previous B reads (or A writes) complete
    {
      const int kk = t & 127;
      const float* tp = text + idx_s[kh * 128 + kk];
      for (int n = (t >> 7); n < 112; n += 2)
        B_lds[n * 136 + kk] =
            (n < NC) ? f2bf(tp[(size_t)n * 512]) : (unsigned short)0;
    }
    __syncthreads();
#pragma unroll
    for (int ks = 0; ks < 4; ++ks) {
      bf16x8 afr = *(const bf16x8*)(A_lds + (mt * 16 + r16) * 264 + kh * 128 +
                                    ks * 32 + q * 8);
#pragma unroll
      for (int nt = 0; nt < 7; ++nt) {
        bf16x8 bfr =
            *(const bf16x8*)(B_lds + (nt * 16 + r16) * 136 + ks * 32 + q * 8);
        acc[nt] = __builtin_amdgcn_mfma_f32_16x16x32_bf16(afr, bfr, acc[nt],
                                                          0, 0, 0);
      }
    }
  }
  __syncthreads();

  // C (64x113 fp32) overlays B_lds (28928 <= 30464 B).
  float* C_lds = reinterpret_cast<float*>(B_lds);
#pragma unroll
  for (int nt = 0; nt < 7; ++nt) {
    const int j2 = nt * 16 + r16;
#pragma unroll
    for (int r = 0; r < 4; ++r) {
      const int m = mt * 16 + q * 4 + r;
      C_lds[m * 113 + j2] = acc[nt][r];
    }
  }
  __syncthreads();

  float* w_lds = reinterpret_cast<float*>(idx_s);  // idx no longer needed
  if (t < 64) {
    const int m = t;
    float mx = -1e30f;
    for (int j2 = 0; j2 < NC; ++j2) mx = fmaxf(mx, C_lds[m * 113 + j2]);
    float sum = 0.0f;
    for (int j2 = 0; j2 < NC; ++j2) sum += expf(C_lds[m * 113 + j2] - mx);
    const float p = expf(C_lds[m * 113 + c] - mx) / sum;
    const float KL = log2f((1.0f + EPSF) / (p + EPSF));
    w_lds[m] = expf(KL * (*pgamma));
  }
  __syncthreads();
  {
    const int j = t;
    float kwv = 0.0f;
#pragma unroll 8
    for (int m = 0; m < 64; ++m) kwv += w_lds[m] * bf2f(A_lds[m * 264 + j]);
    kw_buf[c * 256 + j] = kwv;
  }
}

// ---------------------------------------------------------------------------
// Kernel 4: out[b][c] = alpha*exp(beta*cache-beta) + exp(ls)*dot(fn_b,text_c)
// cache = (1/64) * sum_j fn[b][idx[c][j]] * kw[c][j].  grid 100 x 256.
// Barrier-free: wave w handles b = w, w+4, ... — shuffle reductions only.
// ---------------------------------------------------------------------------
__global__ __launch_bounds__(256) void final_kernel(
    const float* __restrict__ fn, const float* __restrict__ text,
    const int* __restrict__ indices, const float* __restrict__ kw_buf,
    const float* __restrict__ pls, const float* __restrict__ palpha,
    const float* __restrict__ pbeta, float* __restrict__ out) {
  const int c = blockIdx.x;
  const int wv = threadIdx.x >> 6, lane = threadIdx.x & 63;

  int idx4[4];
  float kw4[4];
#pragma unroll
  for (int i = 0; i < 4; ++i) {
    idx4[i] = indices[c * 256 + i * 64 + lane];
    kw4[i] = kw_buf[c * 256 + i * 64 + lane];
  }
  float tc[8];
#pragma unroll
  for (int i = 0; i < 8; ++i) tc[i] = text[c * 512 + i * 64 + lane];
  const float ls = expf(*pls);
  const float alpha = *palpha, beta = *pbeta;

  for (int b = wv; b < 64; b += 4) {
    const float* fr = fn + b * DD;
    float cp = 0.0f, lp = 0.0f;
#pragma unroll
    for (int i = 0; i < 4; ++i) cp += fr[idx4[i]] * kw4[i];
#pragma unroll
    for (int i = 0; i < 8; ++i) lp += fr[i * 64 + lane] * tc[i];
#pragma unroll
    for (int o = 32; o; o >>= 1) {
      cp += __shfl_xor(cp, o);
      lp += __shfl_xor(lp, o);
    }
    if (lane == 0)
      out[b * NC + c] =
          alpha * expf(beta * (cp * (1.0f / 64.0f)) - beta) + ls * lp;
  }
}

// ---------------------------------------------------------------------------
extern "C" void kernel_launch(void* const* d_in, const int* in_sizes, int n_in,
                              void* d_out, int out_size, void* d_ws,
                              size_t ws_size, hipStream_t stream) {
  const float* image = (const float*)d_in[0];
  const float* W = (const float*)d_in[1];
  const float* text = (const float*)d_in[2];
  const float* keys = (const float*)d_in[3];
  const float* pls = (const float*)d_in[4];
  const int* idx = (const int*)d_in[5];
  const float* palpha = (const float*)d_in[6];
  const float* pbeta = (const float*)d_in[7];
  const float* pgamma = (const float*)d_in[8];
  float* out = (float*)d_out;

  char* ws = (char*)d_ws;
  float* f_part = (float*)(ws);                  // 256*64*512*4 = 33554432 B
  float* f_buf = (float*)(ws + 33554432);        // 64*512*4     = 131072 B
  float* fn = (float*)(ws + 33554432 + 131072);  // 64*512*4     = 131072 B
  float* kw = (float*)(ws + 33554432 + 262144);  // 100*256*4    = 102400 B

  gemm_f<<<256, 256, 0, stream>>>(image, W, f_part);
  reduce_f<<<256, 128, 0, stream>>>(f_part, f_buf);
  norm_f<<<64, 64, 0, stream>>>(f_buf, fn);
  wk_kernel<<<NC, 256, 0, stream>>>(text, keys, idx, pgamma, kw);
  final_kernel<<<NC, 256, 0, stream>>>(fn, text, idx, kw, pls, palpha, pbeta,
                                       out);
}